// Round 8
// baseline (252.486 us; speedup 1.0000x reference)
//
#include <hip/hip_runtime.h>
#include <hip/hip_bf16.h>

// AttentionBlock: B=16, N=2048, D=128, fp32 in/out.
// R8 = R7 with host-pass compile fix (MFMA16 guarded by __HIP_DEVICE_COMPILE__).
// S^T via operand swap; P^T fed to PV (mfma 16x16x16) straight from
// registers -> no P LDS round-trip, no b16 scatter. Masks folded upstream
// (eq pre-scaled, masked ek rows zeroed, dead-key {0,1} multiplier).
// Frag-major W layout -> coalesced proj operand loads.

#define SCALE 0.08838834764831845f      // 1/sqrt(128)

typedef __bf16 bf16x8 __attribute__((ext_vector_type(8)));
typedef __bf16 bf16x4 __attribute__((ext_vector_type(4)));
typedef short  s16x4  __attribute__((ext_vector_type(4)));
typedef float  f32x4  __attribute__((ext_vector_type(4)));

static __device__ __forceinline__ f32x4 MFMA16(bf16x4 a, bf16x4 b, f32x4 c) {
#if defined(__HIP_DEVICE_COMPILE__)
    s16x4 sa, sb;
    __builtin_memcpy(&sa, &a, 8);
    __builtin_memcpy(&sb, &b, 8);
    return __builtin_amdgcn_mfma_f32_16x16x16bf16_1k(sa, sb, c, 0, 0, 0);
#else
    (void)a; (void)b;
    return c;   // host stub — never executed
#endif
}

// ---------------- Kernel 0: W -> bf16, fragment-major ----------------
// dst chunk index c = ct*256 + f*64 + quad*16 + col  (so lane reads c = base + lane)
__global__ __launch_bounds__(256) void prep_kernel(
    const float* __restrict__ Wq, const float* __restrict__ Wk,
    const float* __restrict__ Wv, __bf16* __restrict__ wb)
{
    int i = blockIdx.x * 256 + threadIdx.x;          // 0..6143
    int w = i >> 11, c = i & 2047;
    int col = c & 15, quad = (c >> 4) & 3, f = (c >> 6) & 3, ct = c >> 8;
    const float* src = ((w == 0) ? Wq : (w == 1) ? Wk : Wv)
                       + (size_t)(ct * 16 + col) * 128 + f * 32 + quad * 8;
    float4 a = *(const float4*)src, b = *(const float4*)(src + 4);
    bf16x8 t = {(__bf16)a.x, (__bf16)a.y, (__bf16)a.z, (__bf16)a.w,
                (__bf16)b.x, (__bf16)b.y, (__bf16)b.z, (__bf16)b.w};
    *(bf16x8*)&wb[(size_t)w * 16384 + (size_t)c * 8] = t;
}

// ---------------- Kernel 1: projections + masks ----------------
// 512 blocks x 256 thr (4 waves x 16 rows = 64 rows/block).
static __device__ __forceinline__ void do_gemm(
    const __bf16* __restrict__ wb, const float* __restrict__ bias,
    const bf16x8 a[4], __bf16* __restrict__ dst, __bf16* stage,
    const float rmul[4], float sc, bool tp,
    int tid, int wave, int lane, int col, int quad, int rowbase)
{
    f32x4 acc[8];
    #pragma unroll
    for (int ct = 0; ct < 8; ++ct) { f32x4 z = {0.f, 0.f, 0.f, 0.f}; acc[ct] = z; }
    #pragma unroll
    for (int f = 0; f < 4; ++f) {
        #pragma unroll
        for (int ct = 0; ct < 8; ++ct) {
            // fragment-major: fully coalesced, 16 B per lane
            bf16x8 bfr = *(const bf16x8*)&wb[(size_t)(ct * 4 + f) * 512 + lane * 8];
            acc[ct] = __builtin_amdgcn_mfma_f32_16x16x32_bf16(a[f], bfr, acc[ct], 0, 0, 0);
        }
    }
    #pragma unroll
    for (int ct = 0; ct < 8; ++ct) {
        float bv = bias[ct * 16 + col];
        #pragma unroll
        for (int r = 0; r < 4; ++r) {
            float v = (acc[ct][r] + bv) * rmul[r] * sc;
            int rr = wave * 16 + quad * 4 + r;
            if (tp) stage[(ct * 16 + col) * 72 + rr] = (__bf16)v;   // [d][m_local]
            else    stage[rr * 136 + ct * 16 + col] = (__bf16)v;    // [row][d]
        }
    }
    __syncthreads();
    if (!tp) {
        int r = tid >> 2, seg = (tid & 3) * 32;
        uint4* g4 = (uint4*)(dst + (size_t)(rowbase + r) * 128 + seg);
        const uint4* s4 = (const uint4*)&stage[r * 136 + seg];
        g4[0] = s4[0]; g4[1] = s4[1]; g4[2] = s4[2]; g4[3] = s4[3];
    } else {
        int d = tid >> 1, seg = (tid & 1) * 32;
        int bb = rowbase >> 11, mb = rowbase & 2047;
        uint4* g4 = (uint4*)(dst + (size_t)bb * 128 * 2048 + (size_t)d * 2048 + mb + seg);
        const uint4* s4 = (const uint4*)&stage[d * 72 + seg];
        g4[0] = s4[0]; g4[1] = s4[1]; g4[2] = s4[2]; g4[3] = s4[3];
    }
    __syncthreads();
}

__global__ __launch_bounds__(256) void proj_kernel(
    const float* __restrict__ Q, const float* __restrict__ K,
    const int* __restrict__ PM, const __bf16* __restrict__ wb,
    const float* __restrict__ Bq, const float* __restrict__ Bk,
    const float* __restrict__ Bv,
    __bf16* __restrict__ eqb, __bf16* __restrict__ ekb, __bf16* __restrict__ evT,
    float* __restrict__ dmul)
{
    __shared__ __bf16 stage[128 * 72];
    const int tid  = threadIdx.x;
    const int wave = tid >> 6, lane = tid & 63;
    const int col  = lane & 15, quad = lane >> 4;
    const int rowbase = blockIdx.x * 64;
    const int myrow   = rowbase + wave * 16 + col;

    bf16x8 aq[4], ak[4];
    float qs = 0.f, kss = 0.f;
    #pragma unroll
    for (int f = 0; f < 4; ++f) {
        const float* pq = Q + (size_t)myrow * 128 + f * 32 + quad * 8;
        const float* pk = K + (size_t)myrow * 128 + f * 32 + quad * 8;
        float4 q0 = *(const float4*)pq, q1 = *(const float4*)(pq + 4);
        float4 k0 = *(const float4*)pk, k1 = *(const float4*)(pk + 4);
        float qv[8] = {q0.x, q0.y, q0.z, q0.w, q1.x, q1.y, q1.z, q1.w};
        float kv[8] = {k0.x, k0.y, k0.z, k0.w, k1.x, k1.y, k1.z, k1.w};
        #pragma unroll
        for (int j = 0; j < 8; ++j) {
            qs += qv[j]; kss += kv[j];
            aq[f][j] = (__bf16)qv[j];
            ak[f][j] = (__bf16)kv[j];
        }
    }
    qs  += __shfl_xor(qs, 16);  qs  += __shfl_xor(qs, 32);
    kss += __shfl_xor(kss, 16); kss += __shfl_xor(kss, 32);
    int   pmv   = PM[myrow];
    float qpadv = (qs != 0.f) ? 1.f : 0.f;
    float kselv = (pmv != 0) ? 1.f : 0.f;
    if (quad == 0)
        dmul[myrow] = (pmv == 0 && kss == 0.f) ? 0.f : 1.f;

    const float one4[4] = {1.f, 1.f, 1.f, 1.f};
    float qpr[4], kpr[4];
    #pragma unroll
    for (int r = 0; r < 4; ++r) {
        qpr[r] = __shfl(qpadv, quad * 4 + r);
        kpr[r] = __shfl(kselv, quad * 4 + r);
    }

    do_gemm(wb,         Bq, aq, eqb, stage, one4, SCALE, false, tid, wave, lane, col, quad, rowbase);
    do_gemm(wb + 16384, Bk, ak, ekb, stage, kpr,  1.f,   false, tid, wave, lane, col, quad, rowbase);
    do_gemm(wb + 32768, Bv, ak, evT, stage, qpr,  1.f,   true,  tid, wave, lane, col, quad, rowbase);
}

// ---------------- Kernel 2: transposed-S flash attention ----------------
union AttnSmem {
    struct {
        __bf16 ekt[2][32 * 136];   // [half][m][d]           17.0 KB
        __bf16 evt[2][128 * 40];   // [half][d][m] stride 40 20.0 KB (37.9 total)
    } k;
    struct {
        float obuf[2][32 * 132];   // [qwave][q][d]          33.8 KB
        float lbuf[2][32];
    } fin;
};

__global__ __launch_bounds__(256, 3) void attn_kernel(
    const __bf16* __restrict__ eqb, const __bf16* __restrict__ ekb,
    const __bf16* __restrict__ evT, const float* __restrict__ dmul,
    const float* __restrict__ Q, float* __restrict__ out)
{
    __shared__ AttnSmem sm;

    const int tid  = threadIdx.x;
    const int wave = tid >> 6, lane = tid & 63;
    const int col  = lane & 15, quad = lane >> 4;
    const int qw   = wave & 1;           // q-row group of 32
    const int half = wave >> 1;          // key half [half*1024, +1024)
    const int i  = blockIdx.x;
    const int b  = 2 * (i & 7) + ((i >> 3) & 1);
    const int qt = i >> 4;               // 0..31
    const int rowg0 = b * 2048 + qt * 64 + qw * 32;   // +q2*16+col = q row
    const size_t bV = (size_t)b * 128 * 2048;
    const __bf16* ekbase = ekb + (size_t)b * 2048 * 128;

    // Q fragments (pre-scaled eq); used as the B operand of S^T
    bf16x8 aqf[2][4];
    #pragma unroll
    for (int q2 = 0; q2 < 2; ++q2)
        #pragma unroll
        for (int f = 0; f < 4; ++f)
            aqf[q2][f] = *(const bf16x8*)&eqb[(size_t)(rowg0 + q2 * 16 + col) * 128 + f * 32 + quad * 8];

    f32x4 o[2][8];
    float lsum[2] = {0.f, 0.f};
    #pragma unroll
    for (int q2 = 0; q2 < 2; ++q2)
        #pragma unroll
        for (int dt = 0; dt < 8; ++dt) { f32x4 z = {0.f, 0.f, 0.f, 0.f}; o[q2][dt] = z; }

    for (int it = 0; it < 32; ++it) {
        // ---- stage K (2x8KB) and V^T (2x8KB), coalesced b128 ----
        #pragma unroll
        for (int c = 0; c < 4; ++c) {
            int idx = tid + c * 256;
            int h = idx >> 9, r32 = (idx >> 4) & 31, ch = idx & 15;
            *(uint4*)&sm.k.ekt[h][r32 * 136 + ch * 8] =
                *(const uint4*)&ekbase[(size_t)(h * 1024 + it * 32 + r32) * 128 + ch * 8];
        }
        #pragma unroll
        for (int c = 0; c < 4; ++c) {
            int idx = tid + c * 256;
            int h = idx >> 9, d = (idx >> 2) & 127, m8 = (idx & 3) * 8;
            *(uint4*)&sm.k.evt[h][d * 40 + m8] =
                *(const uint4*)&evT[bV + (size_t)d * 2048 + h * 1024 + it * 32 + m8];
        }
        __syncthreads();

        const int mb_h = half * 1024 + it * 32;
        // ---- S^T = K @ Q^T : A = K-frag (LDS), B = Q-frag (regs) ----
        f32x4 s[2][2];
        #pragma unroll
        for (int q2 = 0; q2 < 2; ++q2)
            #pragma unroll
            for (int mt = 0; mt < 2; ++mt) { f32x4 z = {0.f, 0.f, 0.f, 0.f}; s[q2][mt] = z; }
        #pragma unroll
        for (int f = 0; f < 4; ++f) {
            bf16x8 bk[2];
            #pragma unroll
            for (int mt = 0; mt < 2; ++mt)
                bk[mt] = *(const bf16x8*)&sm.k.ekt[half][(mt * 16 + col) * 136 + f * 32 + quad * 8];
            #pragma unroll
            for (int q2 = 0; q2 < 2; ++q2)
                #pragma unroll
                for (int mt = 0; mt < 2; ++mt)
                    s[q2][mt] = __builtin_amdgcn_mfma_f32_16x16x32_bf16(bk[mt], aqf[q2][f], s[q2][mt], 0, 0, 0);
        }

        // ---- e = exp(s) * dead_multiplier; P^T stays in registers ----
        float4 dmv[2];
        dmv[0] = *(const float4*)&dmul[b * 2048 + mb_h + quad * 4];
        dmv[1] = *(const float4*)&dmul[b * 2048 + mb_h + 16 + quad * 4];
        bf16x4 pk[2][2];
        #pragma unroll
        for (int q2 = 0; q2 < 2; ++q2)
            #pragma unroll
            for (int mt = 0; mt < 2; ++mt) {
                const float dm[4] = {dmv[mt].x, dmv[mt].y, dmv[mt].z, dmv[mt].w};
                #pragma unroll
                for (int r = 0; r < 4; ++r) {
                    float e = __expf(s[q2][mt][r]) * dm[r];
                    pk[q2][mt][r] = (__bf16)e;
                    lsum[q2] += e;
                }
            }

        // ---- O^T += V^T @ P^T  (A = V^T b64 from LDS, B = P^T from regs) ----
        #pragma unroll
        for (int dt = 0; dt < 8; ++dt) {
            #pragma unroll
            for (int mt = 0; mt < 2; ++mt) {
                bf16x4 va = *(const bf16x4*)&sm.k.evt[half][(dt * 16 + col) * 40 + mt * 16 + quad * 4];
                o[0][dt] = MFMA16(va, pk[0][mt], o[0][dt]);
                o[1][dt] = MFMA16(va, pk[1][mt], o[1][dt]);
            }
        }
        __syncthreads();
    }

    // ---- l per q-column: reduce over quads (m-rows live across quads) ----
    #pragma unroll
    for (int q2 = 0; q2 < 2; ++q2) {
        lsum[q2] += __shfl_xor(lsum[q2], 16);
        lsum[q2] += __shfl_xor(lsum[q2], 32);
    }

    // ---- combine halves through LDS overlay (o is O^T: row=d, col=q) ----
    if (half == 1) {
        #pragma unroll
        for (int q2 = 0; q2 < 2; ++q2) {
            #pragma unroll
            for (int dt = 0; dt < 8; ++dt) {
                float4 v = {o[q2][dt][0], o[q2][dt][1], o[q2][dt][2], o[q2][dt][3]};
                *(float4*)&sm.fin.obuf[qw][(q2 * 16 + col) * 132 + dt * 16 + quad * 4] = v;
            }
            if (quad == 0) sm.fin.lbuf[qw][q2 * 16 + col] = lsum[q2];
        }
    }
    __syncthreads();
    if (half == 0) {
        #pragma unroll
        for (int q2 = 0; q2 < 2; ++q2) {
            float inv = 1.f / (lsum[q2] + sm.fin.lbuf[qw][q2 * 16 + col]);
            const size_t rowoff = (size_t)(rowg0 + q2 * 16 + col) * 128;
            #pragma unroll
            for (int dt = 0; dt < 8; ++dt) {
                float4 oth = *(const float4*)&sm.fin.obuf[qw][(q2 * 16 + col) * 132 + dt * 16 + quad * 4];
                float4 qres = *(const float4*)&Q[rowoff + dt * 16 + quad * 4];
                float4 v;
                v.x = (o[q2][dt][0] + oth.x) * inv + qres.x;
                v.y = (o[q2][dt][1] + oth.y) * inv + qres.y;
                v.z = (o[q2][dt][2] + oth.z) * inv + qres.z;
                v.w = (o[q2][dt][3] + oth.w) * inv + qres.w;
                *(float4*)&out[rowoff + dt * 16 + quad * 4] = v;
            }
        }
    }
}

extern "C" void kernel_launch(void* const* d_in, const int* in_sizes, int n_in,
                              void* d_out, int out_size, void* d_ws, size_t ws_size,
                              hipStream_t stream)
{
    const float* Q  = (const float*)d_in[0];
    const float* K  = (const float*)d_in[1];
    const int*   PM = (const int*)d_in[2];
    const float* Wq = (const float*)d_in[3];
    const float* Bq = (const float*)d_in[4];
    const float* Wk = (const float*)d_in[5];
    const float* Bk = (const float*)d_in[6];
    const float* Wv = (const float*)d_in[7];
    const float* Bv = (const float*)d_in[8];
    float* out = (float*)d_out;

    const size_t SZE = (size_t)16 * 2048 * 128;
    __bf16* eqb = (__bf16*)d_ws;                    // 8 MB (pre-scaled by 1/sqrt(d))
    __bf16* ekb = eqb + SZE;                        // 8 MB (masked rows zeroed)
    __bf16* evT = ekb + SZE;                        // 8 MB, [B][D][N], q_pad folded
    float* dmul = (float*)(evT + SZE);              // 128 KB: dead-key {0,1}
    __bf16* wb  = (__bf16*)(dmul + 16 * 2048);      // 96 KB: frag-major W

    prep_kernel<<<24, 256, 0, stream>>>(Wq, Wk, Wv, wb);
    proj_kernel<<<512, 256, 0, stream>>>(Q, K, PM, wb, Bq, Bk, Bv,
                                         eqb, ekb, evT, dmul);
    attn_kernel<<<512, 256, 0, stream>>>(eqb, ekb, evT, dmul, Q, out);
}

// Round 9
// 235.761 us; speedup vs baseline: 1.0709x; 1.0709x over previous
//
#include <hip/hip_runtime.h>
#include <hip/hip_bf16.h>

// AttentionBlock: B=16, N=2048, D=128, fp32 in/out.
// R9: fragment-major K/V in global -> attn main loop has ZERO LDS and ZERO
// barriers (every operand load is a coalesced 1KB/512B instruction straight
// from L2). 4-way in-block split-K, LDS only for the final combine.
// Proj split 3-ways across blocks (one GEMM per block, 6 blocks/CU).
// No-max softmax + masks folded upstream (validated R4-R8, absmax 0.03125).

#define SCALE 0.08838834764831845f      // 1/sqrt(128)

typedef __bf16 bf16x8 __attribute__((ext_vector_type(8)));
typedef __bf16 bf16x4 __attribute__((ext_vector_type(4)));
typedef short  s16x4  __attribute__((ext_vector_type(4)));
typedef float  f32x4  __attribute__((ext_vector_type(4)));

static __device__ __forceinline__ f32x4 MFMA16(bf16x4 a, bf16x4 b, f32x4 c) {
#if defined(__HIP_DEVICE_COMPILE__)
    s16x4 sa, sb;
    __builtin_memcpy(&sa, &a, 8);
    __builtin_memcpy(&sb, &b, 8);
    return __builtin_amdgcn_mfma_f32_16x16x16bf16_1k(sa, sb, c, 0, 0, 0);
#else
    (void)a; (void)b;
    return c;   // host stub — never executed
#endif
}

// ---------------- Kernel 0: W -> bf16, fragment-major ----------------
__global__ __launch_bounds__(256) void prep_kernel(
    const float* __restrict__ Wq, const float* __restrict__ Wk,
    const float* __restrict__ Wv, __bf16* __restrict__ wb)
{
    int i = blockIdx.x * 256 + threadIdx.x;          // 0..6143
    int w = i >> 11, c = i & 2047;
    int col = c & 15, quad = (c >> 4) & 3, f = (c >> 6) & 3, ct = c >> 8;
    const float* src = ((w == 0) ? Wq : (w == 1) ? Wk : Wv)
                       + (size_t)(ct * 16 + col) * 128 + f * 32 + quad * 8;
    float4 a = *(const float4*)src, b = *(const float4*)(src + 4);
    bf16x8 t = {(__bf16)a.x, (__bf16)a.y, (__bf16)a.z, (__bf16)a.w,
                (__bf16)b.x, (__bf16)b.y, (__bf16)b.z, (__bf16)b.w};
    *(bf16x8*)&wb[(size_t)w * 16384 + (size_t)c * 8] = t;
}

// ---------------- Kernel 1: projections + masks ----------------
// Grid 1536 = 3 matrices x 512 row-tiles of 64. One GEMM per block.
// w=0: eq (row-major, pre-scaled). w=1: ek -> frag-major ekf (A-operand of
// 16x16x32), padding-masked rows zeroed, writes dmul. w=2: ev -> frag-major
// evf (A-operand of 16x16x16 PV), q_pad folded in.
__global__ __launch_bounds__(256) void proj_kernel(
    const float* __restrict__ Q, const float* __restrict__ K,
    const int* __restrict__ PM, const __bf16* __restrict__ wb,
    const float* __restrict__ Bq, const float* __restrict__ Bk,
    const float* __restrict__ Bv,
    __bf16* __restrict__ eqb, __bf16* __restrict__ ekf, __bf16* __restrict__ evf,
    float* __restrict__ dmul)
{
    __shared__ __bf16 stage[128 * 72];   // 18.4 KB (covers 64*136 = 8704 too)
    const int tid  = threadIdx.x;
    const int wave = tid >> 6, lane = tid & 63;
    const int col  = lane & 15, quad = lane >> 4;
    const int w = blockIdx.x >> 9;                  // 0..2
    const int rowbase = (blockIdx.x & 511) * 64;
    const int myrow   = rowbase + wave * 16 + col;
    const int bb   = rowbase >> 11;                 // batch
    const int m16b = (rowbase & 2047) >> 4;         // 16-row tile base in batch

    // A fragments (+ exact fp32 row sum of the loaded matrix)
    const float* asrc = (w == 0) ? Q : K;
    bf16x8 a[4];
    float ss = 0.f;
    #pragma unroll
    for (int f = 0; f < 4; ++f) {
        const float* p = asrc + (size_t)myrow * 128 + f * 32 + quad * 8;
        float4 v0 = *(const float4*)p, v1 = *(const float4*)(p + 4);
        float vv[8] = {v0.x, v0.y, v0.z, v0.w, v1.x, v1.y, v1.z, v1.w};
        #pragma unroll
        for (int j = 0; j < 8; ++j) { ss += vv[j]; a[f][j] = (__bf16)vv[j]; }
    }

    float rm = 1.f;
    if (w == 1) {
        ss += __shfl_xor(ss, 16); ss += __shfl_xor(ss, 32);   // kss
        int pmv = PM[myrow];
        rm = (pmv != 0) ? 1.f : 0.f;
        if (quad == 0) dmul[myrow] = (pmv == 0 && ss == 0.f) ? 0.f : 1.f;
    } else if (w == 2) {
        float qs = 0.f;
        #pragma unroll
        for (int f = 0; f < 4; ++f) {
            const float* p = Q + (size_t)myrow * 128 + f * 32 + quad * 8;
            float4 v0 = *(const float4*)p, v1 = *(const float4*)(p + 4);
            qs += v0.x + v0.y + v0.z + v0.w + v1.x + v1.y + v1.z + v1.w;
        }
        qs += __shfl_xor(qs, 16); qs += __shfl_xor(qs, 32);
        rm = (qs != 0.f) ? 1.f : 0.f;               // q_pad folded into V
    }
    float rmul[4];
    #pragma unroll
    for (int r = 0; r < 4; ++r) rmul[r] = __shfl(rm, quad * 4 + r);

    const float sc = (w == 0) ? SCALE : 1.f;
    const float* bias = (w == 0) ? Bq : (w == 1) ? Bk : Bv;
    const __bf16* wbp = wb + w * 16384;

    f32x4 acc[8];
    #pragma unroll
    for (int ct = 0; ct < 8; ++ct) { f32x4 z = {0.f, 0.f, 0.f, 0.f}; acc[ct] = z; }
    #pragma unroll
    for (int f = 0; f < 4; ++f) {
        #pragma unroll
        for (int ct = 0; ct < 8; ++ct) {
            bf16x8 bfr = *(const bf16x8*)&wbp[(size_t)(ct * 4 + f) * 512 + lane * 8];
            acc[ct] = __builtin_amdgcn_mfma_f32_16x16x32_bf16(a[f], bfr, acc[ct], 0, 0, 0);
        }
    }
    // C-layout: out-row = quad*4+r, out-d = ct*16+col
    #pragma unroll
    for (int ct = 0; ct < 8; ++ct) {
        float bv = bias[ct * 16 + col];
        #pragma unroll
        for (int r = 0; r < 4; ++r) {
            float v = (acc[ct][r] + bv) * rmul[r] * sc;
            int rr = wave * 16 + quad * 4 + r;
            if (w == 2) stage[(ct * 16 + col) * 72 + rr] = (__bf16)v;   // [d][m]
            else        stage[rr * 136 + ct * 16 + col] = (__bf16)v;    // [m][d]
        }
    }
    __syncthreads();

    if (w == 0) {
        // row-major eq: 64 rows x 256 B (4 thr/row x 64 B)
        int r = tid >> 2, seg = (tid & 3) * 32;
        uint4* g4 = (uint4*)(eqb + (size_t)(rowbase + r) * 128 + seg);
        const uint4* s4 = (const uint4*)&stage[r * 136 + seg];
        g4[0] = s4[0]; g4[1] = s4[1]; g4[2] = s4[2]; g4[3] = s4[3];
    } else if (w == 1) {
        // frag-major ekf: slot s = (m16l*4 + f)*64 + lane, 16 B each
        __bf16* dst = ekf + (size_t)(bb * 128 + m16b) * 4 * 512;
        #pragma unroll
        for (int c = 0; c < 4; ++c) {
            int s = tid + c * 256;
            int l = s & 63, f = (s >> 6) & 3, m = s >> 8;
            *(uint4*)&dst[(size_t)s * 8] =
                *(const uint4*)&stage[(m * 16 + (l & 15)) * 136 + f * 32 + ((l >> 4) & 3) * 8];
        }
    } else {
        // frag-major evf: slot s = (m16l*8 + dt)*64 + lane, 8 B each
        __bf16* dst = evf + (size_t)(bb * 128 + m16b) * 8 * 256;
        #pragma unroll
        for (int c = 0; c < 8; ++c) {
            int s = tid + c * 256;
            int l = s & 63, dt = (s >> 6) & 7, m = s >> 9;
            *(uint2*)&dst[(size_t)s * 4] =
                *(const uint2*)&stage[(dt * 16 + (l & 15)) * 72 + m * 16 + ((l >> 4) & 3) * 4];
        }
    }
}

// ---------------- Kernel 2: barrier-free frag-major flash attention ----------------
// Grid 1024 x 256 thr (4 waves). Block = 32 q-rows; wave w streams key
// quarter [w*512, +512) with zero LDS/barriers. 4-way LDS combine at end.
__global__ __launch_bounds__(256, 4) void attn_kernel(
    const __bf16* __restrict__ eqb, const __bf16* __restrict__ ekf,
    const __bf16* __restrict__ evf, const float* __restrict__ dmul,
    const float* __restrict__ Q, float* __restrict__ out)
{
    __shared__ struct { float obuf[2][32 * 132]; float lbuf[2][32]; } sm;  // 33.8 KB

    const int tid  = threadIdx.x;
    const int wave = tid >> 6, lane = tid & 63;
    const int col  = lane & 15, quad = lane >> 4;
    const int i  = blockIdx.x;
    const int b  = 2 * (i & 7) + ((i >> 3) & 1);   // XCD k hosts batches {2k,2k+1}
    const int qt = i >> 4;                          // 0..63, 32-row q-tiles
    const int rowg0 = b * 2048 + qt * 32;
    const __bf16* ekb_b = ekf + (size_t)b * 2048 * 128;
    const __bf16* evb_b = evf + (size_t)b * 2048 * 128;

    // Q fragments (pre-scaled eq), B-operand of S^T
    bf16x8 aqf[2][4];
    #pragma unroll
    for (int q2 = 0; q2 < 2; ++q2)
        #pragma unroll
        for (int f = 0; f < 4; ++f)
            aqf[q2][f] = *(const bf16x8*)&eqb[(size_t)(rowg0 + q2 * 16 + col) * 128 + f * 32 + quad * 8];

    f32x4 o[2][8];
    float lsum[2] = {0.f, 0.f};
    #pragma unroll
    for (int q2 = 0; q2 < 2; ++q2)
        #pragma unroll
        for (int dt = 0; dt < 8; ++dt) { f32x4 z = {0.f, 0.f, 0.f, 0.f}; o[q2][dt] = z; }

    const int kq0 = wave * 512;          // this wave's key quarter
    for (int it = 0; it < 16; ++it) {
        const int kb = kq0 + it * 32;
        const int m16 = kb >> 4;
        // ---- S^T = K @ Q^T : A = K-frag (coalesced 1KB global), B = regs ----
        f32x4 s[2][2];
        #pragma unroll
        for (int q2 = 0; q2 < 2; ++q2)
            #pragma unroll
            for (int mt = 0; mt < 2; ++mt) { f32x4 z = {0.f, 0.f, 0.f, 0.f}; s[q2][mt] = z; }
        #pragma unroll
        for (int f = 0; f < 4; ++f) {
            bf16x8 bk0 = *(const bf16x8*)&ekb_b[(size_t)((m16 + 0) * 4 + f) * 512 + lane * 8];
            bf16x8 bk1 = *(const bf16x8*)&ekb_b[(size_t)((m16 + 1) * 4 + f) * 512 + lane * 8];
            #pragma unroll
            for (int q2 = 0; q2 < 2; ++q2) {
                s[q2][0] = __builtin_amdgcn_mfma_f32_16x16x32_bf16(bk0, aqf[q2][f], s[q2][0], 0, 0, 0);
                s[q2][1] = __builtin_amdgcn_mfma_f32_16x16x32_bf16(bk1, aqf[q2][f], s[q2][1], 0, 0, 0);
            }
        }
        // ---- e = exp(s) * dead_multiplier; P^T stays in registers ----
        float4 dmv0 = *(const float4*)&dmul[b * 2048 + kb + quad * 4];
        float4 dmv1 = *(const float4*)&dmul[b * 2048 + kb + 16 + quad * 4];
        bf16x4 pk[2][2];
        #pragma unroll
        for (int q2 = 0; q2 < 2; ++q2) {
            #pragma unroll
            for (int mt = 0; mt < 2; ++mt) {
                const float4 dv = mt ? dmv1 : dmv0;
                const float dm[4] = {dv.x, dv.y, dv.z, dv.w};
                #pragma unroll
                for (int r = 0; r < 4; ++r) {
                    float e = __expf(s[q2][mt][r]) * dm[r];
                    pk[q2][mt][r] = (__bf16)e;
                    lsum[q2] += e;
                }
            }
        }
        // ---- O^T += V^T @ P^T : A = V-frag (coalesced 512B global), B = regs ----
        #pragma unroll
        for (int dt = 0; dt < 8; ++dt) {
            bf16x4 va0 = *(const bf16x4*)&evb_b[(size_t)((m16 + 0) * 8 + dt) * 256 + lane * 4];
            bf16x4 va1 = *(const bf16x4*)&evb_b[(size_t)((m16 + 1) * 8 + dt) * 256 + lane * 4];
            o[0][dt] = MFMA16(va0, pk[0][0], o[0][dt]);
            o[0][dt] = MFMA16(va1, pk[0][1], o[0][dt]);
            o[1][dt] = MFMA16(va0, pk[1][0], o[1][dt]);
            o[1][dt] = MFMA16(va1, pk[1][1], o[1][dt]);
        }
    }

    // l per q-column (sum over this wave's quads)
    #pragma unroll
    for (int q2 = 0; q2 < 2; ++q2) {
        lsum[q2] += __shfl_xor(lsum[q2], 16);
        lsum[q2] += __shfl_xor(lsum[q2], 32);
    }

    // ---- 4-way combine: (1,3) dump -> (0,2) add -> 2 dumps -> 0 adds+stores ----
    if (wave & 1) {
        int slot = wave >> 1;
        #pragma unroll
        for (int q2 = 0; q2 < 2; ++q2) {
            #pragma unroll
            for (int dt = 0; dt < 8; ++dt) {
                float4 v = {o[q2][dt][0], o[q2][dt][1], o[q2][dt][2], o[q2][dt][3]};
                *(float4*)&sm.obuf[slot][(q2 * 16 + col) * 132 + dt * 16 + quad * 4] = v;
            }
            if (quad == 0) sm.lbuf[slot][q2 * 16 + col] = lsum[q2];
        }
    }
    __syncthreads();
    if (!(wave & 1)) {
        int slot = wave >> 1;
        #pragma unroll
        for (int q2 = 0; q2 < 2; ++q2) {
            lsum[q2] += sm.lbuf[slot][q2 * 16 + col];
            #pragma unroll
            for (int dt = 0; dt < 8; ++dt) {
                float4 t = *(const float4*)&sm.obuf[slot][(q2 * 16 + col) * 132 + dt * 16 + quad * 4];
                o[q2][dt][0] += t.x; o[q2][dt][1] += t.y;
                o[q2][dt][2] += t.z; o[q2][dt][3] += t.w;
            }
        }
    }
    __syncthreads();
    if (wave == 2) {
        #pragma unroll
        for (int q2 = 0; q2 < 2; ++q2) {
            #pragma unroll
            for (int dt = 0; dt < 8; ++dt) {
                float4 v = {o[q2][dt][0], o[q2][dt][1], o[q2][dt][2], o[q2][dt][3]};
                *(float4*)&sm.obuf[0][(q2 * 16 + col) * 132 + dt * 16 + quad * 4] = v;
            }
            if (quad == 0) sm.lbuf[0][q2 * 16 + col] = lsum[q2];
        }
    }
    __syncthreads();
    if (wave == 0) {
        #pragma unroll
        for (int q2 = 0; q2 < 2; ++q2) {
            float inv = 1.f / (lsum[q2] + sm.lbuf[0][q2 * 16 + col]);
            const size_t rowoff = (size_t)(rowg0 + q2 * 16 + col) * 128;
            #pragma unroll
            for (int dt = 0; dt < 8; ++dt) {
                float4 t = *(const float4*)&sm.obuf[0][(q2 * 16 + col) * 132 + dt * 16 + quad * 4];
                float4 qres = *(const float4*)&Q[rowoff + dt * 16 + quad * 4];
                float4 v;
                v.x = (o[q2][dt][0] + t.x) * inv + qres.x;
                v.y = (o[q2][dt][1] + t.y) * inv + qres.y;
                v.z = (o[q2][dt][2] + t.z) * inv + qres.z;
                v.w = (o[q2][dt][3] + t.w) * inv + qres.w;
                *(float4*)&out[rowoff + dt * 16 + quad * 4] = v;
            }
        }
    }
}

extern "C" void kernel_launch(void* const* d_in, const int* in_sizes, int n_in,
                              void* d_out, int out_size, void* d_ws, size_t ws_size,
                              hipStream_t stream)
{
    const float* Q  = (const float*)d_in[0];
    const float* K  = (const float*)d_in[1];
    const int*   PM = (const int*)d_in[2];
    const float* Wq = (const float*)d_in[3];
    const float* Bq = (const float*)d_in[4];
    const float* Wk = (const float*)d_in[5];
    const float* Bk = (const float*)d_in[6];
    const float* Wv = (const float*)d_in[7];
    const float* Bv = (const float*)d_in[8];
    float* out = (float*)d_out;

    const size_t SZE = (size_t)16 * 2048 * 128;
    __bf16* eqb = (__bf16*)d_ws;                    // 8 MB row-major, pre-scaled
    __bf16* ekf = eqb + SZE;                        // 8 MB frag-major (16x16x32 A)
    __bf16* evf = ekf + SZE;                        // 8 MB frag-major (16x16x16 A)
    float* dmul = (float*)(evf + SZE);              // 128 KB dead-key {0,1}
    __bf16* wb  = (__bf16*)(dmul + 16 * 2048);      // 96 KB frag-major W

    prep_kernel<<<24, 256, 0, stream>>>(Wq, Wk, Wv, wb);
    proj_kernel<<<1536, 256, 0, stream>>>(Q, K, PM, wb, Bq, Bk, Bv,
                                          eqb, ekf, evf, dmul);
    attn_kernel<<<1024, 256, 0, stream>>>(eqb, ekf, evf, dmul, Q, out);
}

// Round 10
// 161.285 us; speedup vs baseline: 1.5655x; 1.4618x over previous
//
#include <hip/hip_runtime.h>
#include <hip/hip_bf16.h>

// AttentionBlock: B=16, N=2048, D=128, fp32 in/out.
// R10: R9 (frag-major K/V from global, zero LDS/barriers in k-loop) +
// explicit software pipeline: K double-buffered across iters, V paired
// b128 issued at iter top, dmul prefetched. launch_bounds(256,2).

#define SCALE 0.08838834764831845f      // 1/sqrt(128)

typedef __bf16 bf16x8 __attribute__((ext_vector_type(8)));
typedef __bf16 bf16x4 __attribute__((ext_vector_type(4)));
typedef short  s16x4  __attribute__((ext_vector_type(4)));
typedef float  f32x4  __attribute__((ext_vector_type(4)));

static __device__ __forceinline__ f32x4 MFMA16(bf16x4 a, bf16x4 b, f32x4 c) {
#if defined(__HIP_DEVICE_COMPILE__)
    s16x4 sa, sb;
    __builtin_memcpy(&sa, &a, 8);
    __builtin_memcpy(&sb, &b, 8);
    return __builtin_amdgcn_mfma_f32_16x16x16bf16_1k(sa, sb, c, 0, 0, 0);
#else
    (void)a; (void)b;
    return c;   // host stub — never executed
#endif
}

static __device__ __forceinline__ bf16x4 lo4(uint4 v) {
    bf16x4 r; uint2 t = {v.x, v.y}; __builtin_memcpy(&r, &t, 8); return r;
}
static __device__ __forceinline__ bf16x4 hi4(uint4 v) {
    bf16x4 r; uint2 t = {v.z, v.w}; __builtin_memcpy(&r, &t, 8); return r;
}

// ---------------- Kernel 0: W -> bf16, fragment-major ----------------
__global__ __launch_bounds__(256) void prep_kernel(
    const float* __restrict__ Wq, const float* __restrict__ Wk,
    const float* __restrict__ Wv, __bf16* __restrict__ wb)
{
    int i = blockIdx.x * 256 + threadIdx.x;          // 0..6143
    int w = i >> 11, c = i & 2047;
    int col = c & 15, quad = (c >> 4) & 3, f = (c >> 6) & 3, ct = c >> 8;
    const float* src = ((w == 0) ? Wq : (w == 1) ? Wk : Wv)
                       + (size_t)(ct * 16 + col) * 128 + f * 32 + quad * 8;
    float4 a = *(const float4*)src, b = *(const float4*)(src + 4);
    bf16x8 t = {(__bf16)a.x, (__bf16)a.y, (__bf16)a.z, (__bf16)a.w,
                (__bf16)b.x, (__bf16)b.y, (__bf16)b.z, (__bf16)b.w};
    *(bf16x8*)&wb[(size_t)w * 16384 + (size_t)c * 8] = t;
}

// ---------------- Kernel 1: projections + masks ----------------
// Grid 1536 = 3 matrices x 512 row-tiles of 64. One GEMM per block.
__global__ __launch_bounds__(256) void proj_kernel(
    const float* __restrict__ Q, const float* __restrict__ K,
    const int* __restrict__ PM, const __bf16* __restrict__ wb,
    const float* __restrict__ Bq, const float* __restrict__ Bk,
    const float* __restrict__ Bv,
    __bf16* __restrict__ eqb, __bf16* __restrict__ ekf, __bf16* __restrict__ evf,
    float* __restrict__ dmul)
{
    __shared__ __bf16 stage[128 * 72];   // 18.4 KB
    const int tid  = threadIdx.x;
    const int wave = tid >> 6, lane = tid & 63;
    const int col  = lane & 15, quad = lane >> 4;
    const int w = blockIdx.x >> 9;                  // 0..2
    const int rowbase = (blockIdx.x & 511) * 64;
    const int myrow   = rowbase + wave * 16 + col;
    const int bb   = rowbase >> 11;                 // batch
    const int m16b = (rowbase & 2047) >> 4;         // 16-row tile base in batch

    const float* asrc = (w == 0) ? Q : K;
    bf16x8 a[4];
    float ss = 0.f;
    #pragma unroll
    for (int f = 0; f < 4; ++f) {
        const float* p = asrc + (size_t)myrow * 128 + f * 32 + quad * 8;
        float4 v0 = *(const float4*)p, v1 = *(const float4*)(p + 4);
        float vv[8] = {v0.x, v0.y, v0.z, v0.w, v1.x, v1.y, v1.z, v1.w};
        #pragma unroll
        for (int j = 0; j < 8; ++j) { ss += vv[j]; a[f][j] = (__bf16)vv[j]; }
    }

    float rm = 1.f;
    if (w == 1) {
        ss += __shfl_xor(ss, 16); ss += __shfl_xor(ss, 32);   // kss
        int pmv = PM[myrow];
        rm = (pmv != 0) ? 1.f : 0.f;
        if (quad == 0) dmul[myrow] = (pmv == 0 && ss == 0.f) ? 0.f : 1.f;
    } else if (w == 2) {
        float qs = 0.f;
        #pragma unroll
        for (int f = 0; f < 4; ++f) {
            const float* p = Q + (size_t)myrow * 128 + f * 32 + quad * 8;
            float4 v0 = *(const float4*)p, v1 = *(const float4*)(p + 4);
            qs += v0.x + v0.y + v0.z + v0.w + v1.x + v1.y + v1.z + v1.w;
        }
        qs += __shfl_xor(qs, 16); qs += __shfl_xor(qs, 32);
        rm = (qs != 0.f) ? 1.f : 0.f;               // q_pad folded into V
    }
    float rmul[4];
    #pragma unroll
    for (int r = 0; r < 4; ++r) rmul[r] = __shfl(rm, quad * 4 + r);

    const float sc = (w == 0) ? SCALE : 1.f;
    const float* bias = (w == 0) ? Bq : (w == 1) ? Bk : Bv;
    const __bf16* wbp = wb + w * 16384;

    f32x4 acc[8];
    #pragma unroll
    for (int ct = 0; ct < 8; ++ct) { f32x4 z = {0.f, 0.f, 0.f, 0.f}; acc[ct] = z; }
    #pragma unroll
    for (int f = 0; f < 4; ++f) {
        #pragma unroll
        for (int ct = 0; ct < 8; ++ct) {
            bf16x8 bfr = *(const bf16x8*)&wbp[(size_t)(ct * 4 + f) * 512 + lane * 8];
            acc[ct] = __builtin_amdgcn_mfma_f32_16x16x32_bf16(a[f], bfr, acc[ct], 0, 0, 0);
        }
    }
    // C-layout: out-row = quad*4+r, out-d = ct*16+col
    #pragma unroll
    for (int ct = 0; ct < 8; ++ct) {
        float bv = bias[ct * 16 + col];
        #pragma unroll
        for (int r = 0; r < 4; ++r) {
            float v = (acc[ct][r] + bv) * rmul[r] * sc;
            int rr = wave * 16 + quad * 4 + r;
            if (w == 2) stage[(ct * 16 + col) * 72 + rr] = (__bf16)v;   // [d][m]
            else        stage[rr * 136 + ct * 16 + col] = (__bf16)v;    // [m][d]
        }
    }
    __syncthreads();

    if (w == 0) {
        // row-major eq: 64 rows x 256 B (4 thr/row x 64 B)
        int r = tid >> 2, seg = (tid & 3) * 32;
        uint4* g4 = (uint4*)(eqb + (size_t)(rowbase + r) * 128 + seg);
        const uint4* s4 = (const uint4*)&stage[r * 136 + seg];
        g4[0] = s4[0]; g4[1] = s4[1]; g4[2] = s4[2]; g4[3] = s4[3];
    } else if (w == 1) {
        // frag-major ekf: slot s = (m16l*4 + f)*64 + lane, 16 B each
        __bf16* dst = ekf + (size_t)bb * 2048 * 128 + (size_t)m16b * 2048;
        #pragma unroll
        for (int c = 0; c < 4; ++c) {
            int s = tid + c * 256;
            int l = s & 63, f = (s >> 6) & 3, m = s >> 8;
            *(uint4*)&dst[(size_t)s * 8] =
                *(const uint4*)&stage[(m * 16 + (l & 15)) * 136 + f * 32 + ((l >> 4) & 3) * 8];
        }
    } else {
        // frag-major evf (b128-paired): slot s = (m16l*4 + dp)*64 + lane, 16 B =
        // {V^T[2dp*16+col][m*16+quad*4..+3], V^T[(2dp+1)*16+col][same]}
        __bf16* dst = evf + (size_t)bb * 2048 * 128 + (size_t)m16b * 2048;
        #pragma unroll
        for (int c = 0; c < 4; ++c) {
            int s = tid + c * 256;
            int l = s & 63, dp = (s >> 6) & 3, m = s >> 8;
            int cl = l & 15, ql = (l >> 4) & 3;
            uint2 xa = *(const uint2*)&stage[((2 * dp) * 16 + cl) * 72 + m * 16 + ql * 4];
            uint2 xb = *(const uint2*)&stage[((2 * dp + 1) * 16 + cl) * 72 + m * 16 + ql * 4];
            uint4 v = {xa.x, xa.y, xb.x, xb.y};
            *(uint4*)&dst[(size_t)s * 8] = v;
        }
    }
}

// ---------------- Kernel 2: pipelined barrier-free attention ----------------
// Grid 1024 x 256 thr (4 waves). Block = 32 q-rows; wave w streams key
// quarter [w*512, +512). K double-buffered, V b128 at iter top.
__global__ __launch_bounds__(256, 2) void attn_kernel(
    const __bf16* __restrict__ eqb, const __bf16* __restrict__ ekf,
    const __bf16* __restrict__ evf, const float* __restrict__ dmul,
    const float* __restrict__ Q, float* __restrict__ out)
{
    __shared__ struct { float obuf[2][32 * 132]; float lbuf[2][32]; } sm;  // 33.8 KB

    const int tid  = threadIdx.x;
    const int wave = tid >> 6, lane = tid & 63;
    const int col  = lane & 15, quad = lane >> 4;
    const int i  = blockIdx.x;
    const int b  = 2 * (i & 7) + ((i >> 3) & 1);   // XCD k hosts batches {2k,2k+1}
    const int qt = i >> 4;                          // 0..63, 32-row q-tiles
    const int rowg0 = b * 2048 + qt * 32;
    const __bf16* ekb_b = ekf + (size_t)b * 2048 * 128;
    const __bf16* evb_b = evf + (size_t)b * 2048 * 128;
    const float*  dmb   = dmul + b * 2048;

    // Q fragments (pre-scaled eq), B-operand of S^T
    bf16x8 aqf[2][4];
    #pragma unroll
    for (int q2 = 0; q2 < 2; ++q2)
        #pragma unroll
        for (int f = 0; f < 4; ++f)
            aqf[q2][f] = *(const bf16x8*)&eqb[(size_t)(rowg0 + q2 * 16 + col) * 128 + f * 32 + quad * 8];

    f32x4 o[2][8];
    float lsum[2] = {0.f, 0.f};
    #pragma unroll
    for (int q2 = 0; q2 < 2; ++q2)
        #pragma unroll
        for (int dt = 0; dt < 8; ++dt) { f32x4 z = {0.f, 0.f, 0.f, 0.f}; o[q2][dt] = z; }

    const int kq0 = wave * 512;          // this wave's key quarter

    // ---- prologue: K frags + dmul for iter 0 ----
    bf16x8 kc[8];
    {
        const int m16 = kq0 >> 4;
        #pragma unroll
        for (int f = 0; f < 4; ++f) {
            kc[f]     = *(const bf16x8*)&ekb_b[(size_t)((m16 + 0) * 4 + f) * 512 + lane * 8];
            kc[4 + f] = *(const bf16x8*)&ekb_b[(size_t)((m16 + 1) * 4 + f) * 512 + lane * 8];
        }
    }
    float4 dm0 = *(const float4*)&dmb[kq0 + quad * 4];
    float4 dm1 = *(const float4*)&dmb[kq0 + 16 + quad * 4];

    for (int it = 0; it < 16; ++it) {
        const int kb = kq0 + it * 32;
        const int m16 = kb >> 4;

        // current V (consumed after S + exp -> ~300 cyc of cover)
        uint4 vc[8];
        #pragma unroll
        for (int dp = 0; dp < 4; ++dp) {
            vc[dp]     = *(const uint4*)&evb_b[(size_t)((m16 + 0) * 4 + dp) * 512 + lane * 8];
            vc[4 + dp] = *(const uint4*)&evb_b[(size_t)((m16 + 1) * 4 + dp) * 512 + lane * 8];
        }
        // next K + dmul (full-iter cover)
        bf16x8 kn[8];
        float4 dn0, dn1;
        if (it < 15) {
            const int m16n = m16 + 2;
            #pragma unroll
            for (int f = 0; f < 4; ++f) {
                kn[f]     = *(const bf16x8*)&ekb_b[(size_t)((m16n + 0) * 4 + f) * 512 + lane * 8];
                kn[4 + f] = *(const bf16x8*)&ekb_b[(size_t)((m16n + 1) * 4 + f) * 512 + lane * 8];
            }
            dn0 = *(const float4*)&dmb[kb + 32 + quad * 4];
            dn1 = *(const float4*)&dmb[kb + 48 + quad * 4];
        }

        // ---- S^T = K @ Q^T ----
        f32x4 s[2][2];
        #pragma unroll
        for (int q2 = 0; q2 < 2; ++q2)
            #pragma unroll
            for (int mt = 0; mt < 2; ++mt) { f32x4 z = {0.f, 0.f, 0.f, 0.f}; s[q2][mt] = z; }
        #pragma unroll
        for (int f = 0; f < 4; ++f) {
            #pragma unroll
            for (int q2 = 0; q2 < 2; ++q2) {
                s[q2][0] = __builtin_amdgcn_mfma_f32_16x16x32_bf16(kc[f],     aqf[q2][f], s[q2][0], 0, 0, 0);
                s[q2][1] = __builtin_amdgcn_mfma_f32_16x16x32_bf16(kc[4 + f], aqf[q2][f], s[q2][1], 0, 0, 0);
            }
        }

        // ---- e = exp(s) * dead_multiplier; P^T stays in registers ----
        const float dmv[2][4] = {{dm0.x, dm0.y, dm0.z, dm0.w},
                                 {dm1.x, dm1.y, dm1.z, dm1.w}};
        bf16x4 pk[2][2];
        #pragma unroll
        for (int q2 = 0; q2 < 2; ++q2)
            #pragma unroll
            for (int mt = 0; mt < 2; ++mt)
                #pragma unroll
                for (int r = 0; r < 4; ++r) {
                    float e = __expf(s[q2][mt][r]) * dmv[mt][r];
                    pk[q2][mt][r] = (__bf16)e;
                    lsum[q2] += e;
                }

        // ---- O^T += V^T @ P^T ----
        #pragma unroll
        for (int dp = 0; dp < 4; ++dp) {
            bf16x4 v0l = lo4(vc[dp]),     v0h = hi4(vc[dp]);
            bf16x4 v1l = lo4(vc[4 + dp]), v1h = hi4(vc[4 + dp]);
            #pragma unroll
            for (int q2 = 0; q2 < 2; ++q2) {
                o[q2][2 * dp]     = MFMA16(v0l, pk[q2][0], o[q2][2 * dp]);
                o[q2][2 * dp]     = MFMA16(v1l, pk[q2][1], o[q2][2 * dp]);
                o[q2][2 * dp + 1] = MFMA16(v0h, pk[q2][0], o[q2][2 * dp + 1]);
                o[q2][2 * dp + 1] = MFMA16(v1h, pk[q2][1], o[q2][2 * dp + 1]);
            }
        }

        // rotate buffers
        if (it < 15) {
            #pragma unroll
            for (int f = 0; f < 8; ++f) kc[f] = kn[f];
            dm0 = dn0; dm1 = dn1;
        }
    }

    // l per q-column (sum over this wave's quads)
    #pragma unroll
    for (int q2 = 0; q2 < 2; ++q2) {
        lsum[q2] += __shfl_xor(lsum[q2], 16);
        lsum[q2] += __shfl_xor(lsum[q2], 32);
    }

    // ---- 4-way combine: (1,3) dump -> (0,2) add -> 2 dumps -> 0 adds+stores ----
    if (wave & 1) {
        int slot = wave >> 1;
        #pragma unroll
        for (int q2 = 0; q2 < 2; ++q2) {
            #pragma unroll
            for (int dt = 0; dt < 8; ++dt) {
                float4 v = {o[q2][dt][0], o[q2][dt][1], o[q2][dt][2], o[q2][dt][3]};
                *(float4*)&sm.obuf[slot][(q2 * 16 + col) * 132 + dt * 16 + quad * 4] = v;
            }
            if (quad == 0) sm.lbuf[slot][q2 * 16 + col] = lsum[q2];
        }
    }
    __syncthreads();
    if (!(wave & 1)) {
        int slot = wave >> 1;
        #pragma unroll
        for (int q2 = 0; q2 < 2; ++q2) {
            lsum[q2] += sm.lbuf[slot][q2 * 16 + col];
            #pragma unroll
            for (int dt = 0; dt < 8; ++dt) {
                float4 t = *(const float4*)&sm.obuf[slot][(q2 * 16 + col) * 132 + dt * 16 + quad * 4];
                o[q2][dt][0] += t.x; o[q2][dt][1] += t.y;
                o[q2][dt][2] += t.z; o[q2][dt][3] += t.w;
            }
        }
    }
    __syncthreads();
    if (wave == 2) {
        #pragma unroll
        for (int q2 = 0; q2 < 2; ++q2) {
            #pragma unroll
            for (int dt = 0; dt < 8; ++dt) {
                float4 v = {o[q2][dt][0], o[q2][dt][1], o[q2][dt][2], o[q2][dt][3]};
                *(float4*)&sm.obuf[0][(q2 * 16 + col) * 132 + dt * 16 + quad * 4] = v;
            }
            if (quad == 0) sm.lbuf[0][q2 * 16 + col] = lsum[q2];
        }
    }
    __syncthreads();
    if (wave == 0) {
        #pragma unroll
        for (int q2 = 0; q2 < 2; ++q2) {
            float inv = 1.f / (lsum[q2] + sm.lbuf[0][q2 * 16 + col]);
            const size_t rowoff = (size_t)(rowg0 + q2 * 16 + col) * 128;
            #pragma unroll
            for (int dt = 0; dt < 8; ++dt) {
                float4 t = *(const float4*)&sm.obuf[0][(q2 * 16 + col) * 132 + dt * 16 + quad * 4];
                float4 qres = *(const float4*)&Q[rowoff + dt * 16 + quad * 4];
                float4 v;
                v.x = (o[q2][dt][0] + t.x) * inv + qres.x;
                v.y = (o[q2][dt][1] + t.y) * inv + qres.y;
                v.z = (o[q2][dt][2] + t.z) * inv + qres.z;
                v.w = (o[q2][dt][3] + t.w) * inv + qres.w;
                *(float4*)&out[rowoff + dt * 16 + quad * 4] = v;
            }
        }
    }
}

extern "C" void kernel_launch(void* const* d_in, const int* in_sizes, int n_in,
                              void* d_out, int out_size, void* d_ws, size_t ws_size,
                              hipStream_t stream)
{
    const float* Q  = (const float*)d_in[0];
    const float* K  = (const float*)d_in[1];
    const int*   PM = (const int*)d_in[2];
    const float* Wq = (const float*)d_in[3];
    const float* Bq = (const float*)d_in[4];
    const float* Wk = (const float*)d_in[5];
    const float* Bk = (const float*)d_in[6];
    const float* Wv = (const float*)d_in[7];
    const float* Bv = (const float*)d_in[8];
    float* out = (float*)d_out;

    const size_t SZE = (size_t)16 * 2048 * 128;
    __bf16* eqb = (__bf16*)d_ws;                    // 8 MB row-major, pre-scaled
    __bf16* ekf = eqb + SZE;                        // 8 MB frag-major (16x16x32 A)
    __bf16* evf = ekf + SZE;                        // 8 MB frag-major b128-paired
    float* dmul = (float*)(evf + SZE);              // 128 KB dead-key {0,1}
    __bf16* wb  = (__bf16*)(dmul + 16 * 2048);      // 96 KB frag-major W

    prep_kernel<<<24, 256, 0, stream>>>(Wq, Wk, Wv, wb);
    proj_kernel<<<1536, 256, 0, stream>>>(Q, K, PM, wb, Bq, Bk, Bv,
                                          eqb, ekf, evf, dmul);
    attn_kernel<<<1024, 256, 0, stream>>>(eqb, ekf, evf, dmul, Q, out);
}